// Round 3
// baseline (248.652 us; speedup 1.0000x reference)
//
#include <hip/hip_runtime.h>

// TSB RNN, wave-per-row affine scan, LDS-transposed I/O.
//
// Per-step linear part is anti-diagonal => over step-PAIRS the map is
// diagonal: c1 -> P*c1 + U, c2 -> Q*c2 + V (independent 1-D affine scans).
// Wave (64 lanes) owns one row; T=4096 in 4 tiles of 1024 steps
// (16 steps/lane), carrying (C1,C2) across tiles.
//
// LDS layout (26,112 B/block -> 6 blocks/CU vs R1's 34.8 KB -> 3):
//   [0 .. WPB*PADREG)          per-wave private own-row tile (in + out)
//   [WPB*PADREG .. +2*PADREG)  block-shared row-0 X tile, DOUBLE-BUFFERED,
//                              staged cooperatively by all 256 threads.
// One __syncthreads per tile; dbuf makes that sufficient (barrier t+1
// proves all reads of buffer (t&1) completed before tile t+2 rewrites it).

constexpr int T_LEN  = 4096;
constexpr int TILE   = 1024;
constexpr int NTILE  = T_LEN / TILE;     // 4
constexpr int CHUNK  = TILE / 64;        // 16 steps per lane per tile
constexpr int WPB    = 4;                // waves per 256-thread block
constexpr int PADREG = TILE + TILE / 16; // 1088 dwords per padded region

__global__ __launch_bounds__(256, 6) void tsb_scan_kernel(
    const float* __restrict__ x,       // (B, T)
    const float* __restrict__ alpha_p,
    const float* __restrict__ beta_p,
    float* __restrict__ out,           // (B, T)
    int B)
{
    __shared__ float lds[(WPB + 2) * PADREG];   // 26,112 B

    const int tid  = threadIdx.x;
    const int wave = tid >> 6;
    const int lane = tid & 63;
    const int row  = blockIdx.x * WPB + wave;   // grid = B/WPB exactly (B=8192)

    float* xl = &lds[wave * PADREG];            // own-row tile (in, then out)

    const float a   = alpha_p[0];
    const float b   = beta_p[0];
    const float oma = 1.0f - a;
    const float omb = 1.0f - b;

    float C1 = 0.f, C2 = 0.f;                   // carry across tiles

    for (int t = 0; t < NTILE; ++t) {
        float* Xl = &lds[(WPB + (t & 1)) * PADREG];  // shared X, dbuf

        // ---- issue all global loads for this tile up front ----
        const float4* Xr4 = (const float4*)(x + t * TILE);
        float4 Xv = Xr4[tid];                   // cooperative: 256 thr x 16 B
        const float4* xr4 = (const float4*)(x + (size_t)row * T_LEN + t * TILE);
        float4 xv[4];
#pragma unroll
        for (int i = 0; i < 4; ++i) xv[i] = xr4[i * 64 + lane];

        // ---- scatter X (cooperative) and own row (per wave) to LDS ----
        {
            int e  = 4 * tid;                   // e%16 in {0,4,8,12}
            int ap = e + (e >> 4);              // same pad-bucket for all 4
            Xl[ap + 0] = Xv.x; Xl[ap + 1] = Xv.y;
            Xl[ap + 2] = Xv.z; Xl[ap + 3] = Xv.w;
        }
        {
            const float* xs = (const float*)xv;
#pragma unroll
            for (int j = 0; j < 16; ++j) {
                int e  = (j >> 2) * 256 + 4 * lane + (j & 3);
                xl[e + (e >> 4)] = xs[j];
            }
        }
        __syncthreads();                        // X visible to all waves

        // ---- gather per-lane contiguous chunk (base 17*lane) ----
        float xc[CHUNK], Xc[CHUNK];
        const int cb = 17 * lane;
#pragma unroll
        for (int j = 0; j < CHUNK; ++j) {
            xc[j] = xl[cb + j];
            Xc[j] = Xl[cb + j];
        }

        // ---- phase 1: compose 8 step-pairs into (p,u | q,v) ----
        float p = 1.f, u = 0.f, q = 1.f, v = 0.f;
#pragma unroll
        for (int h = 0; h < CHUNK / 2; ++h) {
            float x1 = xc[2 * h], x2 = xc[2 * h + 1];
            float X1 = Xc[2 * h], X2 = Xc[2 * h + 1];
            float nz1 = (x1 != 0.f) ? 1.f : 0.f;
            float nz2 = (x2 != 0.f) ? 1.f : 0.f;
            float k1  = (x1 != 0.f) ? oma : 1.f;
            float k2  = (x2 != 0.f) ? oma : 1.f;
            float P = omb * k1;
            float U = omb * a * nz1 * X1 + b * nz2;
            float Q = omb * k2;
            float V = b * k2 * nz1 + a * nz2 * X2;
            u = P * u + U;  p = P * p;
            v = Q * v + V;  q = Q * q;
        }

        // ---- phase 2: inclusive shuffle scan over 64 lanes ----
#pragma unroll
        for (int off = 1; off < 64; off <<= 1) {
            float pi = __shfl_up(p, off, 64);
            float ui = __shfl_up(u, off, 64);
            float qi = __shfl_up(q, off, 64);
            float vi = __shfl_up(v, off, 64);
            if (lane >= off) {
                u = p * ui + u;  p = p * pi;
                v = q * vi + v;  q = q * qi;
            }
        }
        // lane entry state = exclusive prefix applied to tile carry
        float pp = __shfl_up(p, 1, 64), up = __shfl_up(u, 1, 64);
        float qp = __shfl_up(q, 1, 64), vp = __shfl_up(v, 1, 64);
        float c1 = (lane == 0) ? C1 : (pp * C1 + up);
        float c2 = (lane == 0) ? C2 : (qp * C2 + vp);
        // tile exit carry from lane 63's inclusive map (uses OLD C1,C2)
        float p63 = __shfl(p, 63, 64), u63 = __shfl(u, 63, 64);
        float q63 = __shfl(q, 63, 64), v63 = __shfl(v, 63, 64);
        float C1n = p63 * C1 + u63;
        float C2n = q63 * C2 + v63;
        C1 = C1n;  C2 = C2n;

        // ---- phase 3: exact replay; outputs overwrite own chunk in LDS ----
#pragma unroll
        for (int j = 0; j < CHUNK; ++j) {
            float xj = xc[j];
            bool  nz = (xj != 0.f);
            float c2n = nz ? (a * Xc[j] + oma * c1) : c1;
            float c1n = (nz ? b : 0.f) + omb * c2;
            c1 = c1n;  c2 = c2n;
            xl[cb + j] = c1 * c2;
        }

        // ---- coalesced global stores (full lines, wave-private LDS) ----
        float4* or4 = (float4*)(out + (size_t)row * T_LEN + t * TILE);
#pragma unroll
        for (int i = 0; i < 4; ++i) {
            float os[4];
#pragma unroll
            for (int k = 0; k < 4; ++k) {
                int e = i * 256 + 4 * lane + k;
                os[k] = xl[e + (e >> 4)];
            }
            or4[i * 64 + lane] = *(float4*)os;
        }
    }
}

extern "C" void kernel_launch(void* const* d_in, const int* in_sizes, int n_in,
                              void* d_out, int out_size, void* d_ws, size_t ws_size,
                              hipStream_t stream) {
    const float* x     = (const float*)d_in[0];
    const float* alpha = (const float*)d_in[1];
    const float* beta  = (const float*)d_in[2];
    float* out = (float*)d_out;

    const int B = in_sizes[0] / T_LEN;   // 8192
    const int blocks = (B + WPB - 1) / WPB;
    tsb_scan_kernel<<<blocks, 64 * WPB, 0, stream>>>(x, alpha, beta, out, B);
}

// Round 4
// 242.690 us; speedup vs baseline: 1.0246x; 1.0246x over previous
//
#include <hip/hip_runtime.h>

// TSB RNN, wave-per-row affine scan — LDS-free version.
//
// Per-step linear part is anti-diagonal => over step-PAIRS the map is
// diagonal: c1 -> P*c1 + U, c2 -> Q*c2 + V (two independent 1-D affine
// scans). Wave (64 lanes) owns one row. Each lane owns 4 CONTIGUOUS
// timesteps (one float4) of a 256-step subtile, so the coalesced global
// load IS the transpose — no LDS, no barriers, no bank conflicts.
// 16 subtiles chain the carry (C1,C2) in-wave.
//
// Per subtile: compose 2 step-pair maps locally -> 6-stage __shfl_up
// inclusive scan of (p,u,q,v) -> exact 4-step replay -> coalesced float4
// store straight from registers.
//
// R2 post-mortem note: no __launch_bounds__ min-waves arg — forcing 6
// waves/EU squeezed VGPR to 40 and spilled to scratch (FETCH +54 MB,
// WRITE +33 MB). This kernel's working set is ~50 VGPRs; let the
// allocator breathe.

constexpr int T_LEN = 4096;
constexpr int SUB   = 256;            // timesteps per subtile (4 per lane)
constexpr int NSUB  = T_LEN / SUB;    // 16
constexpr int WPB   = 4;              // waves per 256-thread block

__global__ __launch_bounds__(256) void tsb_scan_kernel(
    const float* __restrict__ x,      // (B, T)
    const float* __restrict__ alpha_p,
    const float* __restrict__ beta_p,
    float* __restrict__ out,          // (B, T)
    int B)
{
    const int tid  = threadIdx.x;
    const int lane = tid & 63;
    const int row  = blockIdx.x * WPB + (tid >> 6);
    if (row >= B) return;

    const float a   = alpha_p[0];
    const float b   = beta_p[0];
    const float oma = 1.0f - a;
    const float omb = 1.0f - b;

    const float4* xr = (const float4*)(x + (size_t)row * T_LEN);
    const float4* Xr = (const float4*)x;               // row 0 (shared X quirk)
    float4*       orp = (float4*)(out + (size_t)row * T_LEN);

    float C1 = 0.f, C2 = 0.f;                          // carry across subtiles

    // prefetch subtile 0
    float4 xn = xr[lane];
    float4 Xn = Xr[lane];

    for (int s = 0; s < NSUB; ++s) {
        float4 xc4 = xn, Xc4 = Xn;
        if (s + 1 < NSUB) {                            // prefetch next subtile
            xn = xr[(s + 1) * 64 + lane];
            Xn = Xr[(s + 1) * 64 + lane];
        }
        const float* xc = (const float*)&xc4;
        const float* Xc = (const float*)&Xc4;

        // ---- compose this lane's 4 steps as 2 step-pairs: c -> {p,q}c + {u,v}
        float p = 1.f, u = 0.f, q = 1.f, v = 0.f;
#pragma unroll
        for (int h = 0; h < 2; ++h) {
            float x1 = xc[2 * h], x2 = xc[2 * h + 1];
            float X1 = Xc[2 * h], X2 = Xc[2 * h + 1];
            float nz1 = (x1 != 0.f) ? 1.f : 0.f;
            float nz2 = (x2 != 0.f) ? 1.f : 0.f;
            float k1  = (x1 != 0.f) ? oma : 1.f;
            float k2  = (x2 != 0.f) ? oma : 1.f;
            float P = omb * k1;
            float U = omb * a * nz1 * X1 + b * nz2;
            float Q = omb * k2;
            float V = b * k2 * nz1 + a * nz2 * X2;
            u = P * u + U;  p = P * p;
            v = Q * v + V;  q = Q * q;
        }

        // ---- inclusive shuffle scan of affine maps across 64 lanes ----
#pragma unroll
        for (int off = 1; off < 64; off <<= 1) {
            float pi = __shfl_up(p, off, 64);
            float ui = __shfl_up(u, off, 64);
            float qi = __shfl_up(q, off, 64);
            float vi = __shfl_up(v, off, 64);
            if (lane >= off) {
                u = p * ui + u;  p = p * pi;
                v = q * vi + v;  q = q * qi;
            }
        }
        // lane entry state = exclusive prefix applied to subtile carry
        float pp = __shfl_up(p, 1, 64), up = __shfl_up(u, 1, 64);
        float qp = __shfl_up(q, 1, 64), vp = __shfl_up(v, 1, 64);
        float c1 = (lane == 0) ? C1 : (pp * C1 + up);
        float c2 = (lane == 0) ? C2 : (qp * C2 + vp);
        // subtile exit carry from lane 63's inclusive map (uses OLD carry)
        float p63 = __shfl(p, 63, 64), u63 = __shfl(u, 63, 64);
        float q63 = __shfl(q, 63, 64), v63 = __shfl(v, 63, 64);
        float nC1 = p63 * C1 + u63;
        float nC2 = q63 * C2 + v63;
        C1 = nC1;  C2 = nC2;

        // ---- exact 4-step replay, store one coalesced float4 ----
        float os[4];
#pragma unroll
        for (int j = 0; j < 4; ++j) {
            bool  nz  = (xc[j] != 0.f);
            float c2n = nz ? (a * Xc[j] + oma * c1) : c1;
            float c1n = (nz ? b : 0.f) + omb * c2;
            c1 = c1n;  c2 = c2n;
            os[j] = c1 * c2;
        }
        orp[s * 64 + lane] = *(const float4*)os;
    }
}

extern "C" void kernel_launch(void* const* d_in, const int* in_sizes, int n_in,
                              void* d_out, int out_size, void* d_ws, size_t ws_size,
                              hipStream_t stream) {
    const float* x     = (const float*)d_in[0];
    const float* alpha = (const float*)d_in[1];
    const float* beta  = (const float*)d_in[2];
    float* out = (float*)d_out;

    const int B = in_sizes[0] / T_LEN;   // 8192
    const int blocks = (B + WPB - 1) / WPB;
    tsb_scan_kernel<<<blocks, 64 * WPB, 0, stream>>>(x, alpha, beta, out, B);
}